// Round 10
// baseline (1451.046 us; speedup 1.0000x reference)
//
#include <hip/hip_runtime.h>
#include <hip/hip_bf16.h>

// CfC cell via three bf16 MFMA GEMMs, 256x256 8-phase schedule (round-2
// structure verbatim) with 32x32x16 MFMA fragments (hipBLASLt/HK shape:
// +15-20% rate, half the MFMA instruction count). acc[4][2] f32x16/wave.

typedef unsigned short u16;
typedef __bf16 bf16x8_t __attribute__((ext_vector_type(8)));
typedef float f32x4_t __attribute__((ext_vector_type(4)));
typedef float f32x16_t __attribute__((ext_vector_type(16)));
typedef u16 u16x8_t __attribute__((ext_vector_type(8)));

#define M_TOTAL 131072  // B*T = 128*1024

__device__ __forceinline__ u16 f2bf(float f) {
  union { float f; unsigned u; } v; v.f = f;
  unsigned r = v.u + 0x7FFFu + ((v.u >> 16) & 1u);  // RNE
  return (u16)(r >> 16);
}

__device__ __forceinline__ float fast_tanh(float x) {
  x = fminf(15.f, fmaxf(-15.f, x));
  float e = __expf(2.f * x);
  return (e - 1.f) * __builtin_amdgcn_rcpf(e + 1.f);
}

__device__ __forceinline__ float fast_sigmoid(float x) {
  return __builtin_amdgcn_rcpf(1.f + __expf(-x));
}

__device__ __forceinline__ void gload_lds16(const void* g, void* l) {
  __builtin_amdgcn_global_load_lds(
      (const __attribute__((address_space(1))) unsigned int*)g,
      (__attribute__((address_space(3))) unsigned int*)l,
      16, 0, 0);
}

// ---------------- prep kernels ----------------

__global__ void prep_x(const float* __restrict__ inp, const float* __restrict__ hx,
                       u16* __restrict__ X) {
  const int total = M_TOTAL * 96;
  int stride = gridDim.x * blockDim.x;
  for (int v = blockIdx.x * blockDim.x + threadIdx.x; v < total; v += stride) {
    int m = v / 96; int c = v - m * 96;
    const float* src = (c < 32) ? (inp + (size_t)m * 256 + (c << 3))
                                : (hx + (size_t)m * 512 + ((size_t)(c - 32) << 3));
    f32x4_t a = *(const f32x4_t*)src;
    f32x4_t b = *(const f32x4_t*)(src + 4);
    u16x8_t o;
    o[0]=f2bf(a[0]); o[1]=f2bf(a[1]); o[2]=f2bf(a[2]); o[3]=f2bf(a[3]);
    o[4]=f2bf(b[0]); o[5]=f2bf(b[1]); o[6]=f2bf(b[2]); o[7]=f2bf(b[3]);
    *(u16x8_t*)(X + (size_t)m * 768 + (c << 3)) = o;
  }
}

// all weight transposes ([n][k] row-major) + head-interleave + bias interleave
__global__ void prep_w(const float* __restrict__ W0, const float* __restrict__ W1,
                       const float* __restrict__ Wf1, const float* __restrict__ Wf2,
                       const float* __restrict__ Wta, const float* __restrict__ Wtb,
                       const float* __restrict__ bf1, const float* __restrict__ bf2,
                       const float* __restrict__ bta, const float* __restrict__ btb,
                       u16* __restrict__ W0T, u16* __restrict__ W1T,
                       u16* __restrict__ WhT, float* __restrict__ biasi) {
  int id = blockIdx.x * blockDim.x + threadIdx.x;
  u16x8_t o;
  if (id < 98304) {                       // W0T[n][k] = W0[k][n], K=768
    int n = id / 96, k0 = (id - n * 96) << 3;
#pragma unroll
    for (int i = 0; i < 8; ++i) o[i] = f2bf(W0[(size_t)(k0 + i) * 1024 + n]);
    *(u16x8_t*)(W0T + (size_t)n * 768 + k0) = o;
  } else if (id < 229376) {               // W1T[n][k] = W1[k][n], K=1024
    int id2 = id - 98304; int n = id2 >> 7, k0 = (id2 & 127) << 3;
#pragma unroll
    for (int i = 0; i < 8; ++i) o[i] = f2bf(W1[(size_t)(k0 + i) * 1024 + n]);
    *(u16x8_t*)(W1T + (size_t)n * 1024 + k0) = o;
  } else if (id < 491520) {               // WhT head-interleaved per 16-col block
    int id3 = id - 229376; int head = id3 >> 16; int id4 = id3 & 65535;
    int n = id4 >> 7, k0 = (id4 & 127) << 3;
    const float* W = (head == 0) ? Wf1 : (head == 1) ? Wf2 : (head == 2) ? Wta : Wtb;
#pragma unroll
    for (int i = 0; i < 8; ++i) o[i] = f2bf(W[(size_t)(k0 + i) * 512 + n]);
    int row = ((n >> 4) << 6) + head * 16 + (n & 15);
    *(u16x8_t*)(WhT + (size_t)row * 1024 + k0) = o;
  } else if (id < 492032) {               // interleaved head bias
    int h = id - 491520;
    int base = ((h >> 4) << 6) + (h & 15);
    biasi[base +  0] = bf1[h];
    biasi[base + 16] = bf2[h];
    biasi[base + 32] = bta[h];
    biasi[base + 48] = btb[h];
  }
}

// ---------------- 256x256 8-phase GEMM, 32x32x16 fragments ----------------
// C = A[M,K] * BT[NI,K]^T. 512 thr = 8 waves (2Mx4N), per-wave 128x64 =
// 4 m-blocks x 2 n-blocks of 32x32. BK=64 (two 32-col LDS k-slabs).
// LDS: A[2buf][2slab][256][32] at 0, B same at 65536 -> 128 KiB.
// st_16x32 swizzle: stage = linear LDS dest + inverse-swizzled global source;
// reads XOR bit5 with row-bit3.

#define BARX()  do { __builtin_amdgcn_s_barrier(); __builtin_amdgcn_sched_barrier(0); } while(0)
#define LGKM0() do { asm volatile("s_waitcnt lgkmcnt(0)" ::: "memory"); __builtin_amdgcn_sched_barrier(0); } while(0)

template<int K, int NI, int EPI>
__global__ __launch_bounds__(512, 2)
void gemm32(const u16* __restrict__ A, const u16* __restrict__ BT,
            const float* __restrict__ bias, const float* __restrict__ ts,
            void* __restrict__ Cout)
{
  constexpr int NTn = NI / 256;
  constexpr int NITER = K / 128;           // 2 K-tiles (of 64) per iter
  constexpr int NWG = (M_TOTAL / 256) * NTn;
  __shared__ __align__(16) char smem[131072];

  const int bid0 = blockIdx.x;
  const int bid = (bid0 & 7) * (NWG >> 3) + (bid0 >> 3);   // XCD swizzle (NWG%8==0)
  const int mt = bid / NTn, nt = bid % NTn;
  const int tileM = mt * 256, tileN = nt * 256;

  const int tid = threadIdx.x;
  const int w = tid >> 6, l = tid & 63;
  const int wm = w >> 2, wn = w & 3;

  // ---- staging addressing (verbatim round 2): chunk c = 2w+j (1024B),
  // slab kk=c>>3, rows (c&7)*16 + (l>>2), colbyte ((l&3)<<4) ^ ((l>>5)&1)<<5
  const int c0 = w * 2, c1 = w * 2 + 1;
  const int kkS0 = c0 >> 3, kkS1 = c1 >> 3;
  const int rS0 = (c0 & 7) * 16 + (l >> 2);
  const int rS1 = (c1 & 7) * 16 + (l >> 2);
  const int cbS = ((l & 3) << 4) ^ (((l >> 5) & 1) << 5);
  const int cA0 = (c0 & 7) * 1024, cA1 = (c1 & 7) * 1024;
  const u16* aSrc = A + (size_t)tileM * K + (cbS >> 1);
  const u16* bSrc = BT + (size_t)tileN * K + (cbS >> 1);

  // ---- 32x32 fragment read addressing: row = l&31, k-group = l>>5 (8 elems);
  // byte col for kk-half = kk*32 + (l>>5)*16, XOR swizzle bit5 = (l&8)<<2
  const int xb = (l & 8) << 2;
  const int rc0 = ((l >> 5) << 4) + xb;          // kk=0
  const int rc1 = ((l >> 5) << 4) + (32 ^ xb);   // kk=1
  const char* aBase = (const char*)smem + (wm * 128 + (l & 31)) * 64;
  const char* bBase = (const char*)smem + 65536 + (wn * 64 + (l & 31)) * 64;

  f32x16_t acc[4][2];
#pragma unroll
  for (int i = 0; i < 4; ++i)
#pragma unroll
    for (int j = 0; j < 2; ++j)
#pragma unroll
      for (int e = 0; e < 16; ++e) acc[i][j][e] = 0.f;

  bf16x8_t aq[2][2][2], b0q[2][2], b1q[2][2];   // [mbL][slab][kk], [slab][kk]

#define STAGE_A(d, h, t) do { \
    gload_lds16(aSrc + (size_t)((h)*128 + rS0) * K + (t)*64 + kkS0*32, \
                smem + (d)*32768 + kkS0*16384 + (h)*8192 + cA0); \
    gload_lds16(aSrc + (size_t)((h)*128 + rS1) * K + (t)*64 + kkS1*32, \
                smem + (d)*32768 + kkS1*16384 + (h)*8192 + cA1); } while(0)

#define STAGE_B(d, h, t) do { \
    gload_lds16(bSrc + (size_t)((h)*128 + rS0) * K + (t)*64 + kkS0*32, \
                smem + 65536 + (d)*32768 + kkS0*16384 + (h)*8192 + cA0); \
    gload_lds16(bSrc + (size_t)((h)*128 + rS1) * K + (t)*64 + kkS1*32, \
                smem + 65536 + (d)*32768 + kkS1*16384 + (h)*8192 + cA1); } while(0)

#define READ_A(d, mp) do { \
    _Pragma("unroll") for (int s_ = 0; s_ < 2; ++s_) { \
      aq[0][s_][0] = *(const bf16x8_t*)(aBase + (d)*32768 + s_*16384 + ((mp)*2+0)*2048 + rc0); \
      aq[0][s_][1] = *(const bf16x8_t*)(aBase + (d)*32768 + s_*16384 + ((mp)*2+0)*2048 + rc1); \
      aq[1][s_][0] = *(const bf16x8_t*)(aBase + (d)*32768 + s_*16384 + ((mp)*2+1)*2048 + rc0); \
      aq[1][s_][1] = *(const bf16x8_t*)(aBase + (d)*32768 + s_*16384 + ((mp)*2+1)*2048 + rc1); \
    } } while(0)

#define READ_B(d, BQ, nb) do { \
    _Pragma("unroll") for (int s_ = 0; s_ < 2; ++s_) { \
      BQ[s_][0] = *(const bf16x8_t*)(bBase + (d)*32768 + s_*16384 + (nb)*2048 + rc0); \
      BQ[s_][1] = *(const bf16x8_t*)(bBase + (d)*32768 + s_*16384 + (nb)*2048 + rc1); \
    } } while(0)

#define MFMAQ(mp, nb, BQ) do { \
    __builtin_amdgcn_s_setprio(1); \
    _Pragma("unroll") for (int s_ = 0; s_ < 2; ++s_) \
      _Pragma("unroll") for (int kk_ = 0; kk_ < 2; ++kk_) \
        _Pragma("unroll") for (int mL_ = 0; mL_ < 2; ++mL_) \
          acc[(mp)*2+mL_][nb] = __builtin_amdgcn_mfma_f32_32x32x16_bf16( \
              aq[mL_][s_][kk_], BQ[s_][kk_], acc[(mp)*2+mL_][nb], 0, 0, 0); \
    __builtin_amdgcn_s_setprio(0); \
  } while(0)

  // prologue: buf0 = tile0 (all 4 halves), buf1 = tile1 B-halves
  STAGE_A(0, 0, 0); STAGE_A(0, 1, 0);
  STAGE_B(0, 0, 0); STAGE_B(0, 1, 0);
  STAGE_B(1, 0, 1); STAGE_B(1, 1, 1);
  asm volatile("s_waitcnt vmcnt(4)" ::: "memory");  // buf0 resident; buf1.B in flight
  BARX();

#pragma unroll 1
  for (int i = 0; i < NITER; ++i) {
    const int t1 = 2*i + 1, t2 = 2*i + 2, t3 = 2*i + 3;
    const bool more = (i + 1 < NITER);
    // ph1: A(buf0,m01)+B(buf0,n0); stage buf1.Ah0 (t1)
    READ_A(0, 0); READ_B(0, b0q, 0);
    STAGE_A(1, 0, t1);
    BARX(); LGKM0(); MFMAQ(0, 0, b0q); BARX();
    // ph2: B(buf0,n1); stage buf1.Ah1 (t1)
    READ_B(0, b1q, 1);
    STAGE_A(1, 1, t1);
    BARX(); LGKM0(); MFMAQ(0, 1, b1q); BARX();
    // ph3: A(buf0,m23); stage buf0.Bh0 (t2)
    READ_A(0, 1);
    if (more) STAGE_B(0, 0, t2);
    BARX(); LGKM0(); MFMAQ(1, 0, b0q); BARX();
    // ph4: stage buf0.Bh1 (t2); vmcnt -> buf1 (t1) fully resident
    if (more) STAGE_B(0, 1, t2);
    BARX(); MFMAQ(1, 1, b1q);
    if (more) { asm volatile("s_waitcnt vmcnt(4)" ::: "memory"); }
    else      { asm volatile("s_waitcnt vmcnt(0)" ::: "memory"); }
    BARX();
    // ph5: A(buf1,m01)+B(buf1,n0); stage buf0.Ah0 (t2)
    READ_A(1, 0); READ_B(1, b0q, 0);
    if (more) STAGE_A(0, 0, t2);
    BARX(); LGKM0(); MFMAQ(0, 0, b0q); BARX();
    // ph6: B(buf1,n1); stage buf0.Ah1 (t2)
    READ_B(1, b1q, 1);
    if (more) STAGE_A(0, 1, t2);
    BARX(); LGKM0(); MFMAQ(0, 1, b1q); BARX();
    // ph7: A(buf1,m23); stage buf1.Bh0 (t3)
    READ_A(1, 1);
    if (more) STAGE_B(1, 0, t3);
    BARX(); LGKM0(); MFMAQ(1, 0, b0q); BARX();
    // ph8: stage buf1.Bh1 (t3); vmcnt -> buf0 (t2) fully resident
    if (more) STAGE_B(1, 1, t3);
    BARX(); MFMAQ(1, 1, b1q);
    asm volatile("s_waitcnt vmcnt(4)" ::: "memory");
    BARX();
  }

  // ---------------- epilogue ----------------
  // 32x32 C/D layout (m74/m101): col = lane&31, row = (reg&3)+8*(reg>>2)+4*(lane>>5)
  const int colB = tileN + wn * 64 + (l & 31);
  const int rBase = tileM + wm * 128 + ((l >> 5) << 2);

  if constexpr (EPI == 0) {
    const float bv0 = bias[colB], bv1 = bias[colB + 32];
    u16* C = (u16*)Cout;
#pragma unroll
    for (int mb = 0; mb < 4; ++mb)
#pragma unroll
      for (int r = 0; r < 16; ++r) {
        const int row = rBase + mb * 32 + (r & 3) + ((r >> 2) << 3);
        float v0 = acc[mb][0][r] + bv0;
        float v1 = acc[mb][1][r] + bv1;
        C[(size_t)row * NI + colB]      = f2bf(1.7159f * fast_tanh(0.666f * v0));
        C[(size_t)row * NI + colB + 32] = f2bf(1.7159f * fast_tanh(0.666f * v1));
      }
  } else {
    // heads per 16-col block: head = nb*2 + ((l>>4)&1); lanes l and l^16 share
    // (rows, h) and hold complementary head pairs -> shfl_xor(16) exchange.
    const float bv0 = bias[colB], bv1 = bias[colB + 32];
    const int hg = ((tileN >> 6) + wn) * 16 + (l & 15);
    const bool low = ((l & 16) == 0);
    float* out = (float*)Cout;
#pragma unroll
    for (int mb = 0; mb < 4; ++mb)
#pragma unroll
      for (int r = 0; r < 16; ++r) {
        float a0 = acc[mb][0][r] + bv0;    // low: ff1-raw, high: ff2-raw
        float a1 = acc[mb][1][r] + bv1;    // low: ta,      high: tb
        float e0 = __shfl_xor(a0, 16);
        float e1 = __shfl_xor(a1, 16);
        float ff1r = low ? a0 : e0;
        float ff2r = low ? e0 : a0;
        float tar  = low ? a1 : e1;
        float tbr  = low ? e1 : a1;
        const int row = rBase + mb * 32 + (r & 3) + ((r >> 2) << 3);
        const float tsv = ts[row];
        float s = fast_sigmoid(tar * tsv + tbr);
        float f1 = fast_tanh(ff1r);
        float f2 = fast_tanh(ff2r);
        if (low) out[(size_t)row * 512 + hg] = f1 + s * (f2 - f1);
      }
  }
#undef STAGE_A
#undef STAGE_B
#undef READ_A
#undef READ_B
#undef MFMAQ
}

// ---------------- launch ----------------

extern "C" void kernel_launch(void* const* d_in, const int* in_sizes, int n_in,
                              void* d_out, int out_size, void* d_ws, size_t ws_size,
                              hipStream_t stream) {
  const float* input = (const float*)d_in[0];
  const float* hx    = (const float*)d_in[1];
  const float* ts    = (const float*)d_in[2];
  const float* W0    = (const float*)d_in[3];
  const float* b0    = (const float*)d_in[4];
  const float* W1    = (const float*)d_in[5];
  const float* b1    = (const float*)d_in[6];
  const float* Wff1  = (const float*)d_in[7];
  const float* bff1  = (const float*)d_in[8];
  const float* Wff2  = (const float*)d_in[9];
  const float* bff2  = (const float*)d_in[10];
  const float* Wta   = (const float*)d_in[11];
  const float* bta   = (const float*)d_in[12];
  const float* Wtb   = (const float*)d_in[13];
  const float* btb   = (const float*)d_in[14];

  const size_t WS_NEEDED = 544743424ull;
  if (ws_size < WS_NEEDED) return;
  char* ws = (char*)d_ws;
  u16* Xcat = (u16*)(ws);                      // [M,768] bf16, reused as X2 [M,1024]
  u16* X2   = (u16*)(ws);
  u16* X1   = (u16*)(ws + 268435456ull);       // [M,1024] bf16
  u16* W0T  = (u16*)(ws + 536870912ull);       // [1024][768]
  u16* W1T  = (u16*)(ws + 538443776ull);       // [1024][1024]
  u16* WhT  = (u16*)(ws + 540540928ull);       // [2048][1024] head-interleaved
  float* biasi = (float*)(ws + 544735232ull);  // [2048]

  prep_x<<<2048, 256, 0, stream>>>(input, hx, Xcat);
  prep_w<<<1922, 256, 0, stream>>>(W0, W1, Wff1, Wff2, Wta, Wtb,
                                   bff1, bff2, bta, btb, W0T, W1T, WhT, biasi);

  gemm32<768, 1024, 0><<<2048, 512, 0, stream>>>(Xcat, W0T, b0, nullptr, X1);
  gemm32<1024, 1024, 0><<<2048, 512, 0, stream>>>(X1, W1T, b1, nullptr, X2);
  gemm32<1024, 2048, 1><<<4096, 512, 0, stream>>>(X2, WhT, biasi, ts, d_out);
}